// Round 1
// baseline (332.665 us; speedup 1.0000x reference)
//
#include <hip/hip_runtime.h>
#include <math.h>

#define SUM_H 224
#define SUM_W 221
#define ROWP  224   // padded row stride (floats); level offsets {0,128,192} are 16B-aligned

typedef float f32x4 __attribute__((ext_vector_type(4)));
typedef float f32x2 __attribute__((ext_vector_type(2)));

// ---------------------------------------------------------------------------
// Kernel 1: per selected gene, softmax widths -> bin-edge table only.
//   bl_t : bin edges (leading 0, trailing forced 1.0), level offs {0,128,192},
//          counts {128,64,32} (fills the 224-float row exactly).
// ---------------------------------------------------------------------------
__global__ __launch_bounds__(64) void gene_tables_kernel(
    const float* __restrict__ widths_weight,
    const int*   __restrict__ genes_oi,
    float* __restrict__ bl_t,
    int n_genes)
{
    int g = blockIdx.x;
    if (g >= n_genes) return;
    int gi = genes_oi[g];
    int l  = threadIdx.x;

    const float* wsrc  = widths_weight + (size_t)gi * SUM_W;
    float*       bldst = bl_t + (size_t)g * ROWP;

    const int ns[3]   = {128, 64, 32};
    const int woff[3] = {0, 127, 190};   // offsets inside the 221-wide source row
    const int toff[3] = {0, 128, 192};   // offsets inside padded table rows

    for (int lev = 0; lev < 3; lev++) {
        int m  = ns[lev] - 1;            // number of widths
        int j0 = 2 * l, j1 = 2 * l + 1;  // lane l owns elems 2l, 2l+1
        float u0 = (j0 < m) ? wsrc[woff[lev] + j0] : -1e30f;
        float u1 = (j1 < m) ? wsrc[woff[lev] + j1] : -1e30f;
        float mx = fmaxf(u0, u1);
        #pragma unroll
        for (int msk = 32; msk >= 1; msk >>= 1)
            mx = fmaxf(mx, __shfl_xor(mx, msk, 64));
        float e0 = (j0 < m) ? __expf(u0 - mx) : 0.f;
        float e1 = (j1 < m) ? __expf(u1 - mx) : 0.f;
        float local = e0 + e1;
        float incl  = local;
        #pragma unroll
        for (int off = 1; off < 64; off <<= 1) {
            float t = __shfl_up(incl, off, 64);
            if (l >= off) incl += t;
        }
        float total = __shfl(incl, 63, 64);
        float inv   = 1.0f / total;
        float excl  = incl - local;
        float c0 = (excl + e0) * inv;
        float c1 = (excl + e0 + e1) * inv;
        if (j0 <= m - 2) bldst[toff[lev] + j0 + 1] = c0;
        if (j1 <= m - 2) bldst[toff[lev] + j1 + 1] = c1;
        if (l == 0) {
            bldst[toff[lev]]     = 0.0f;
            bldst[toff[lev] + m] = 1.0f;
        }
    }
}

// ---------------------------------------------------------------------------
// DPP 16-lane rotate-reductions (a DPP "row" == our 16-lane point group).
// ---------------------------------------------------------------------------
template<int CTRL>
__device__ __forceinline__ float dppf(float v) {
    return __builtin_bit_cast(float,
        __builtin_amdgcn_update_dpp(0, __builtin_bit_cast(int, v), CTRL, 0xF, 0xF, true));
}
template<int CTRL>
__device__ __forceinline__ int dppi(int v) {
    return __builtin_amdgcn_update_dpp(0, v, CTRL, 0xF, 0xF, true);
}
__device__ __forceinline__ float row16_sum(float v) {
    v += dppf<0x121>(v);
    v += dppf<0x122>(v);
    v += dppf<0x124>(v);
    v += dppf<0x128>(v);
    return v;
}
__device__ __forceinline__ int row16_sum_i(int v) {
    v += dppi<0x121>(v);
    v += dppi<0x122>(v);
    v += dppi<0x124>(v);
    v += dppi<0x128>(v);
    return v;
}

// ---------------------------------------------------------------------------
// Kernel 2: 16 lanes per point; lane e owns contiguous elems [K*e, K*e+K).
// wh[] arrays eliminated (derived from bl at use sites) -> lower VGPR liveness.
// ---------------------------------------------------------------------------
template<int K>
struct Lvl {
    float E[K + 1];   // staged uh, then E = exp(uh+dh); E[K] = neighbor's E[0]
    float bl[K];      // bin edges owned by this lane
    float s[K];       // staged dh, then trapezoid masses
    float bln;        // neighbor lane's bl[0]
    float inva;       // 1/area   (uniform across group)
    float larea;      // log(area)
};

template<int K>
__device__ __forceinline__ void lvl_fetch(const float* __restrict__ dh,
                                          const float* __restrict__ uh,
                                          const float* __restrict__ blp,
                                          int e, Lvl<K>& L)
{
    const int j = K * e;
    // delta is a 224 MB single-use stream -> nontemporal; uh/bl are hot L2 tables.
    if constexpr (K == 8) {
        *(f32x4*)&L.E[0]  = *(const f32x4*)(uh  + j);
        *(f32x4*)&L.E[4]  = *(const f32x4*)(uh  + j + 4);
        *(f32x4*)&L.s[0]  = __builtin_nontemporal_load((const f32x4*)(dh + j));
        *(f32x4*)&L.s[4]  = __builtin_nontemporal_load((const f32x4*)(dh + j + 4));
        *(f32x4*)&L.bl[0] = *(const f32x4*)(blp + j);
        *(f32x4*)&L.bl[4] = *(const f32x4*)(blp + j + 4);
    } else if constexpr (K == 4) {
        *(f32x4*)&L.E[0]  = *(const f32x4*)(uh  + j);
        *(f32x4*)&L.s[0]  = __builtin_nontemporal_load((const f32x4*)(dh + j));
        *(f32x4*)&L.bl[0] = *(const f32x4*)(blp + j);
    } else {
        *(f32x2*)&L.E[0]  = *(const f32x2*)(uh  + j);
        *(f32x2*)&L.s[0]  = __builtin_nontemporal_load((const f32x2*)(dh + j));
        *(f32x2*)&L.bl[0] = *(const f32x2*)(blp + j);
    }
}

template<int K>
__device__ __forceinline__ void lvl_finish(int e, Lvl<K>& L)
{
    L.bln = __shfl_down(L.bl[0], 1, 16);          // junk at e==15, masked below
    #pragma unroll
    for (int k = 0; k < K; k++) L.E[k] = __expf(L.E[k] + L.s[k]);
    L.E[K] = __shfl_down(L.E[0], 1, 16);          // junk at e==15, masked below
    #pragma unroll
    for (int k = 0; k < K - 1; k++)
        L.s[k] = (L.E[k] + L.E[k + 1]) * (0.5f * (L.bl[k + 1] - L.bl[k]));
    {
        float sl = (L.E[K - 1] + L.E[K]) * (0.5f * (L.bln - L.bl[K - 1]));
        L.s[K - 1] = (e == 15) ? 0.f : sl;        // mass N-1 does not exist
    }
    float a = 0.f;
    #pragma unroll
    for (int k = 0; k < K; k++) a += L.s[k];
    a = row16_sum(a);
    L.inva  = __builtin_amdgcn_rcpf(a);
    L.larea = __logf(a);
}

// Single predicate loop drives bin count, partial CDF, AND running-select of
// the 4 apply fields (replaces the former 7-step x 4-field select chain).
// Lane-15 last slot is gated (bin N-1 doesn't exist) so the x==1.0 clamp path
// selects bin N-2, matching the old chain+clamp semantics.
template<int N, int K>
__device__ __forceinline__ void lvl_apply(const Lvl<K>& L, int e, float& x, float& lad)
{
    constexpr int LOGK = (K == 8) ? 3 : (K == 4) ? 2 : 1;

    int   cnt  = (x >= L.bl[0]) ? 1 : 0;
    float part = 0.f;
    float El = L.E[0], Er = L.E[1], inb = L.bl[0], blr = L.bl[1];
    #pragma unroll
    for (int k = 1; k < K; k++) {
        bool pk = (x >= L.bl[k]);
        cnt  += pk ? 1 : 0;
        part += pk ? L.s[k - 1] : 0.f;
        bool sel = pk && ((k < K - 1) || (e != 15));   // element existence gate
        float cr = (k == K - 1) ? L.bln : L.bl[k + 1];
        El  = sel ? L.E[k]     : El;
        Er  = sel ? L.E[k + 1] : Er;
        inb = sel ? L.bl[k]    : inb;
        blr = sel ? cr         : blr;
    }
    part += (x >= L.bln) ? L.s[K - 1] : 0.f;      // e15: s[K-1]==0, junk pred harmless

    cnt  = row16_sum_i(cnt);
    part = row16_sum(part);

    int idx = cnt - 1;                 // cnt >= 1 since bl[0]=0 <= x
    if (idx > N - 2) idx = N - 2;      // x==1.0; out-clip absorbs part's off-by-one
    const int owner = idx >> LOGK;

    El  = __shfl(El,  owner, 16);
    Er  = __shfl(Er,  owner, 16);
    inb = __shfl(inb, owner, 16);
    blr = __shfl(blr, owner, 16);

    float w     = blr - inb;
    float dE    = Er - El;
    float alpha = (x - inb) * __builtin_amdgcn_rcpf(w);
    // raw-unit poly: alpha^2*(0.5*w*dE) + alpha*(El*w) + part, then * 1/area
    float poly  = fmaf(fmaf(0.5f * w * dE, alpha, El * w), alpha, part);
    float outv  = poly * L.inva;
    lad += __logf(fmaf(alpha, dE, El)) - L.larea;
    x = __builtin_amdgcn_fmed3f(outv, 0.0f, 1.0f);
}

// __launch_bounds__(256,4): cap VGPR at 128 -> >=4 waves/SIMD. Live-register
// estimate ~70-100 after wh[] elimination; revert the ",4" if spills appear.
__global__ __launch_bounds__(256, 4) void spline_kernel(
    const float* __restrict__ x_in,
    const float* __restrict__ delta,
    const int*   __restrict__ lgx,
    const int*   __restrict__ genes_oi,
    const float* __restrict__ heights_weight,
    const float* __restrict__ bl_t,
    float* __restrict__ out,
    float* __restrict__ lad_out,
    int n_points)
{
    int tid = blockIdx.x * blockDim.x + threadIdx.x;
    int p = tid >> 4;
    int e = tid & 15;
    if (p >= n_points) return;

    int g  = lgx[p];
    int gi = genes_oi[g];
    const float* dh = delta          + (size_t)p  * SUM_H;
    const float* uh = heights_weight + (size_t)gi * SUM_H;  // rows are 224 = ROWP
    const float* bl = bl_t + (size_t)g * ROWP;

    Lvl<8> L0; Lvl<4> L1; Lvl<2> L2;
    // all 13 global loads issued before the first dependent use
    lvl_fetch<8>(dh,       uh,       bl,       e, L0);
    lvl_fetch<4>(dh + 128, uh + 128, bl + 128, e, L1);
    lvl_fetch<2>(dh + 192, uh + 192, bl + 192, e, L2);
    float x   = x_in[p];
    float lad = 0.f;

    lvl_finish<8>(e, L0);
    lvl_finish<4>(e, L1);
    lvl_apply<128, 8>(L0, e, x, lad);
    lvl_finish<2>(e, L2);
    lvl_apply<64,  4>(L1, e, x, lad);
    lvl_apply<32,  2>(L2, e, x, lad);

    if (e == 0) {
        out[p]     = x;
        lad_out[p] = lad;
    }
}

extern "C" void kernel_launch(void* const* d_in, const int* in_sizes, int n_in,
                              void* d_out, int out_size, void* d_ws, size_t ws_size,
                              hipStream_t stream)
{
    const float* x        = (const float*)d_in[0];
    const float* delta    = (const float*)d_in[1];
    const float* hw       = (const float*)d_in[2];
    const float* ww       = (const float*)d_in[3];
    const int*   genes_oi = (const int*)  d_in[4];
    const int*   lgx      = (const int*)  d_in[5];

    int n_points   = in_sizes[0];
    int n_genes_oi = in_sizes[4];

    float* bl_t = (float*)d_ws;

    hipLaunchKernelGGL(gene_tables_kernel, dim3(n_genes_oi), dim3(64), 0, stream,
                       ww, genes_oi, bl_t, n_genes_oi);

    const int threads = 256;
    const int ppb     = threads / 16;
    const int blocks  = (n_points + ppb - 1) / ppb;
    hipLaunchKernelGGL(spline_kernel, dim3(blocks), dim3(threads), 0, stream,
                       x, delta, lgx, genes_oi, hw, bl_t,
                       (float*)d_out, (float*)d_out + n_points, n_points);
}

// Round 2
// 330.268 us; speedup vs baseline: 1.0073x; 1.0073x over previous
//
#include <hip/hip_runtime.h>
#include <math.h>

#define SUM_H 224
#define SUM_W 221
#define TROW  448   // packed per-gene table row: [ bl(224) | uh(224) ], 16B-aligned offsets

typedef float f32x4 __attribute__((ext_vector_type(4)));
typedef float f32x2 __attribute__((ext_vector_type(2)));

// ---------------------------------------------------------------------------
// Kernel 1: per selected gene g:
//   trow[0..224)   = bin edges (levels at {0,128,192}, counts {128,64,32},
//                    leading 0 / trailing 1.0 per level)
//   trow[224..448) = gathered copy of heights_weight[genes_oi[g]]
// Spline kernel then needs only lgx[p] -> one dense 1792-B row (no genes_oi hop).
// ---------------------------------------------------------------------------
__global__ __launch_bounds__(64) void gene_tables_kernel(
    const float* __restrict__ widths_weight,
    const float* __restrict__ heights_weight,
    const int*   __restrict__ genes_oi,
    float* __restrict__ tab,
    int n_genes)
{
    int g = blockIdx.x;
    if (g >= n_genes) return;
    int gi = genes_oi[g];
    int l  = threadIdx.x;

    const float* wsrc = widths_weight  + (size_t)gi * SUM_W;
    const float* hsrc = heights_weight + (size_t)gi * SUM_H;
    float*       trow = tab + (size_t)g * TROW;

    // gather uh row: 224 floats = 56 float4, lanes 0..55
    if (l < 56) ((f32x4*)(trow + 224))[l] = ((const f32x4*)hsrc)[l];

    const int ns[3]   = {128, 64, 32};
    const int woff[3] = {0, 127, 190};   // offsets inside the 221-wide source row
    const int toff[3] = {0, 128, 192};   // offsets inside the packed bl block

    for (int lev = 0; lev < 3; lev++) {
        int m  = ns[lev] - 1;            // number of widths
        int j0 = 2 * l, j1 = 2 * l + 1;  // lane l owns elems 2l, 2l+1
        float u0 = (j0 < m) ? wsrc[woff[lev] + j0] : -1e30f;
        float u1 = (j1 < m) ? wsrc[woff[lev] + j1] : -1e30f;
        float mx = fmaxf(u0, u1);
        #pragma unroll
        for (int msk = 32; msk >= 1; msk >>= 1)
            mx = fmaxf(mx, __shfl_xor(mx, msk, 64));
        float e0 = (j0 < m) ? __expf(u0 - mx) : 0.f;
        float e1 = (j1 < m) ? __expf(u1 - mx) : 0.f;
        float local = e0 + e1;
        float incl  = local;
        #pragma unroll
        for (int off = 1; off < 64; off <<= 1) {
            float t = __shfl_up(incl, off, 64);
            if (l >= off) incl += t;
        }
        float total = __shfl(incl, 63, 64);
        float inv   = 1.0f / total;
        float excl  = incl - local;
        float c0 = (excl + e0) * inv;
        float c1 = (excl + e0 + e1) * inv;
        if (j0 <= m - 2) trow[toff[lev] + j0 + 1] = c0;
        if (j1 <= m - 2) trow[toff[lev] + j1 + 1] = c1;
        if (l == 0) {
            trow[toff[lev]]     = 0.0f;
            trow[toff[lev] + m] = 1.0f;
        }
    }
}

// ---------------------------------------------------------------------------
// DPP 16-lane rotate-reductions (a DPP "row" == our 16-lane point group).
// ---------------------------------------------------------------------------
template<int CTRL>
__device__ __forceinline__ float dppf(float v) {
    return __builtin_bit_cast(float,
        __builtin_amdgcn_update_dpp(0, __builtin_bit_cast(int, v), CTRL, 0xF, 0xF, true));
}
__device__ __forceinline__ float row16_sum(float v) {
    v += dppf<0x121>(v);
    v += dppf<0x122>(v);
    v += dppf<0x124>(v);
    v += dppf<0x128>(v);
    return v;
}

// ---------------------------------------------------------------------------
// Kernel 2: 16 lanes per point, TWO points per lane-group (independent chains
// -> 2x ILP on every latency stall, 2x MLP per wave, half the waves).
// ---------------------------------------------------------------------------
template<int K>
struct Lvl {
    float E[K + 1];   // staged uh, then E = exp(uh+dh); E[K] = neighbor's E[0]
    float bl[K];      // bin edges owned by this lane
    float s[K];       // staged dh, then trapezoid masses
    float bln;        // neighbor lane's bl[0]
    float inva;       // 1/area   (uniform across group)
    float larea;      // log(area)
};

template<int K>
__device__ __forceinline__ void fetch_delta(const float* __restrict__ dh, int e, Lvl<K>& L)
{
    const int j = K * e;
    // delta is a 224 MB single-use stream -> nontemporal
    if constexpr (K == 8) {
        *(f32x4*)&L.s[0] = __builtin_nontemporal_load((const f32x4*)(dh + j));
        *(f32x4*)&L.s[4] = __builtin_nontemporal_load((const f32x4*)(dh + j + 4));
    } else if constexpr (K == 4) {
        *(f32x4*)&L.s[0] = __builtin_nontemporal_load((const f32x4*)(dh + j));
    } else {
        *(f32x2*)&L.s[0] = __builtin_nontemporal_load((const f32x2*)(dh + j));
    }
}

template<int K>
__device__ __forceinline__ void fetch_tab(const float* __restrict__ bl,
                                          const float* __restrict__ uh,
                                          int e, Lvl<K>& L)
{
    const int j = K * e;
    if constexpr (K == 8) {
        *(f32x4*)&L.E[0]  = *(const f32x4*)(uh + j);
        *(f32x4*)&L.E[4]  = *(const f32x4*)(uh + j + 4);
        *(f32x4*)&L.bl[0] = *(const f32x4*)(bl + j);
        *(f32x4*)&L.bl[4] = *(const f32x4*)(bl + j + 4);
    } else if constexpr (K == 4) {
        *(f32x4*)&L.E[0]  = *(const f32x4*)(uh + j);
        *(f32x4*)&L.bl[0] = *(const f32x4*)(bl + j);
    } else {
        *(f32x2*)&L.E[0]  = *(const f32x2*)(uh + j);
        *(f32x2*)&L.bl[0] = *(const f32x2*)(bl + j);
    }
}

template<int K>
__device__ __forceinline__ void lvl_finish(int e, Lvl<K>& L)
{
    L.bln = __shfl_down(L.bl[0], 1, 16);          // junk at e==15, masked below
    #pragma unroll
    for (int k = 0; k < K; k++) L.E[k] = __expf(L.E[k] + L.s[k]);
    L.E[K] = __shfl_down(L.E[0], 1, 16);          // junk at e==15, masked below
    #pragma unroll
    for (int k = 0; k < K - 1; k++)
        L.s[k] = (L.E[k] + L.E[k + 1]) * (0.5f * (L.bl[k + 1] - L.bl[k]));
    {
        float sl = (L.E[K - 1] + L.E[K]) * (0.5f * (L.bln - L.bl[K - 1]));
        L.s[K - 1] = (e == 15) ? 0.f : sl;        // mass N-1 does not exist
    }
    float a = 0.f;
    #pragma unroll
    for (int k = 0; k < K; k++) a += L.s[k];
    a = row16_sum(a);
    L.inva  = __builtin_amdgcn_rcpf(a);
    L.larea = __logf(a);
}

// Ballot-based owner: edges are sorted, so lane e's FIRST edge (index K*e) is
// <= x  iff  e <= idx>>LOGK. popcount(group ballot)-1 == idx>>LOGK exactly
// (incl. the x==1.0 case, where the lane-15 select gate forces bin N-2).
// Running select over per-lane predicates picks slot idx&(K-1) in the owner.
template<int N, int K>
__device__ __forceinline__ void lvl_apply(const Lvl<K>& L, int e,
                                          unsigned long long gmask,
                                          float& x, float& lad)
{
    float part = 0.f;
    float El = L.E[0], Er = L.E[1], inb = L.bl[0], blr = L.bl[1];
    #pragma unroll
    for (int k = 1; k < K; k++) {
        bool pk = (x >= L.bl[k]);
        part += pk ? L.s[k - 1] : 0.f;
        bool sel = pk && ((k < K - 1) || (e != 15));   // element existence gate
        float cr = (k == K - 1) ? L.bln : L.bl[k + 1];
        El  = sel ? L.E[k]     : El;
        Er  = sel ? L.E[k + 1] : Er;
        inb = sel ? L.bl[k]    : inb;
        blr = sel ? cr         : blr;
    }
    part += (x >= L.bln) ? L.s[K - 1] : 0.f;      // e15: s[K-1]==0, junk pred harmless

    part = row16_sum(part);
    unsigned long long b = __ballot(x >= L.bl[0]);
    int owner = (int)__popcll(b & gmask) - 1;     // 0..15 group-local

    El  = __shfl(El,  owner, 16);
    Er  = __shfl(Er,  owner, 16);
    inb = __shfl(inb, owner, 16);
    blr = __shfl(blr, owner, 16);

    float w     = blr - inb;
    float dE    = Er - El;
    float alpha = (x - inb) * __builtin_amdgcn_rcpf(w);
    // raw-unit poly: alpha^2*(0.5*w*dE) + alpha*(El*w) + part, then * 1/area
    float poly  = fmaf(fmaf(0.5f * w * dE, alpha, El * w), alpha, part);
    float outv  = poly * L.inva;
    lad += __logf(fmaf(alpha, dE, El)) - L.larea;
    x = __builtin_amdgcn_fmed3f(outv, 0.0f, 1.0f);
}

// 2 points/group: ~130-140 live VGPRs -> __launch_bounds__(256,3) (cap ~170,
// no spill); 3 waves/SIMD x 8 points/wave = 24 points in flight per SIMD.
__global__ __launch_bounds__(256, 3) void spline_kernel(
    const float* __restrict__ x_in,
    const float* __restrict__ delta,
    const int*   __restrict__ lgx,
    const float* __restrict__ tab,
    float* __restrict__ out,
    float* __restrict__ lad_out,
    int n_points)
{
    int tid = blockIdx.x * blockDim.x + threadIdx.x;
    int grp = tid >> 4;
    int e   = tid & 15;
    int p0  = grp * 2;
    if (p0 >= n_points) return;
    bool has1 = (p0 + 1 < n_points);

    // chain root: gene ids + x (p0 is even -> int2/float2 aligned)
    int g0, g1;
    float x0, x1;
    if (has1) {
        int2   gg = *(const int2*)  (lgx  + p0);
        float2 xx = *(const float2*)(x_in + p0);
        g0 = gg.x; g1 = gg.y; x0 = xx.x; x1 = xx.y;
    } else {
        g0 = lgx[p0]; g1 = g0; x0 = x_in[p0]; x1 = x0;
    }

    const float* dh0 = delta + (size_t)p0 * SUM_H;
    const float* dh1 = dh0 + SUM_H;

    Lvl<8> A0, B0; Lvl<4> A1, B1; Lvl<2> A2, B2;

    // delta loads are independent of the gene lookup -> issue all 12 first
    fetch_delta<8>(dh0,       e, A0);
    fetch_delta<8>(dh1,       e, B0);
    fetch_delta<4>(dh0 + 128, e, A1);
    fetch_delta<4>(dh1 + 128, e, B1);
    fetch_delta<2>(dh0 + 192, e, A2);
    fetch_delta<2>(dh1 + 192, e, B2);

    const float* t0 = tab + (size_t)g0 * TROW;
    const float* t1 = tab + (size_t)g1 * TROW;
    fetch_tab<8>(t0,       t0 + 224, e, A0);
    fetch_tab<8>(t1,       t1 + 224, e, B0);
    fetch_tab<4>(t0 + 128, t0 + 352, e, A1);
    fetch_tab<4>(t1 + 128, t1 + 352, e, B1);
    fetch_tab<2>(t0 + 192, t0 + 416, e, A2);
    fetch_tab<2>(t1 + 192, t1 + 416, e, B2);

    unsigned long long gmask = 0xFFFFull << (threadIdx.x & 48);
    float lad0 = 0.f, lad1 = 0.f;

    // interleave the two independent chains
    lvl_finish<8>(e, A0);
    lvl_finish<8>(e, B0);
    lvl_apply<128, 8>(A0, e, gmask, x0, lad0);
    lvl_finish<4>(e, A1);
    lvl_finish<4>(e, B1);
    lvl_apply<128, 8>(B0, e, gmask, x1, lad1);
    lvl_apply<64,  4>(A1, e, gmask, x0, lad0);
    lvl_finish<2>(e, A2);
    lvl_finish<2>(e, B2);
    lvl_apply<64,  4>(B1, e, gmask, x1, lad1);
    lvl_apply<32,  2>(A2, e, gmask, x0, lad0);
    lvl_apply<32,  2>(B2, e, gmask, x1, lad1);

    if (e == 0) {
        if (has1) {
            *(f32x2*)(out     + p0) = (f32x2){x0,   x1};
            *(f32x2*)(lad_out + p0) = (f32x2){lad0, lad1};
        } else {
            out[p0]     = x0;
            lad_out[p0] = lad0;
        }
    }
}

extern "C" void kernel_launch(void* const* d_in, const int* in_sizes, int n_in,
                              void* d_out, int out_size, void* d_ws, size_t ws_size,
                              hipStream_t stream)
{
    const float* x        = (const float*)d_in[0];
    const float* delta    = (const float*)d_in[1];
    const float* hw       = (const float*)d_in[2];
    const float* ww       = (const float*)d_in[3];
    const int*   genes_oi = (const int*)  d_in[4];
    const int*   lgx      = (const int*)  d_in[5];

    int n_points   = in_sizes[0];
    int n_genes_oi = in_sizes[4];

    float* tab = (float*)d_ws;   // n_genes_oi * TROW floats (500*448*4 = 896 KB)

    hipLaunchKernelGGL(gene_tables_kernel, dim3(n_genes_oi), dim3(64), 0, stream,
                       ww, hw, genes_oi, tab, n_genes_oi);

    const int threads = 256;
    const int gpb     = threads / 16;            // 16-lane groups per block
    const int ngrp    = (n_points + 1) / 2;      // 2 points per group
    const int blocks  = (ngrp + gpb - 1) / gpb;
    hipLaunchKernelGGL(spline_kernel, dim3(blocks), dim3(threads), 0, stream,
                       x, delta, lgx, tab,
                       (float*)d_out, (float*)d_out + n_points, n_points);
}